// Round 21
// baseline (83.189 us; speedup 1.0000x reference)
//
#include <hip/hip_runtime.h>
#include <hip/hip_bf16.h>
#include <math.h>

// SpectralConv2d (FNO): B=16, Cin=Cout=32, H=W=256, MODES=16x16.
// kF = R20 (radix-4 main loop, P+Q radix tail). kI h-split: grid 1024
// (bo, hq), stages 1-2 duplicated, stage 3 w-col-per-lane (U preload 32
// VGPR) -> 4 blocks/CU, 16 waves/CU: stage-1/2 of one block overlaps
// stage-3 writes of another.

#define PI_F 3.14159265358979323846f

__global__ __launch_bounds__(256, 2) void kF(const float* __restrict__ x,
                                             float2* __restrict__ xsub) {
    __shared__ float2 tw[256];
    __shared__ float2 Ts[16][4][65];     // [m][c][l]; later overlaid by Q[16][4][65]
    __shared__ float2 redP[4128];        // union: red[4][4][4][64] / P[16][2][129]
    auto red = reinterpret_cast<float2 (*)[4][4][64]>(redP);
    auto P   = reinterpret_cast<float2 (*)[2][129]>(redP);
    auto Q   = reinterpret_cast<float2 (*)[4][65]>(&Ts[0][0][0]);   // [16][4][65]

    const int t = threadIdx.x;
    { float ang = (2.0f * PI_F / 256.0f) * (float)t;
      tw[t] = make_float2(__cosf(ang), __sinf(ang)); }
    __syncthreads();

    const int bi = blockIdx.x;
    const float4* xq = (const float4*)(x + (size_t)bi * 65536);  // row r -> xq[r*64+l]
    const int l = t & 63, wv = t >> 6;
    const int h0 = wv * 16;              // wave covers h0..h0+15 (x4 rows each)

    float Tr[4][16], Ti[4][16];          // [c][m]
#pragma unroll
    for (int c = 0; c < 4; ++c)
#pragma unroll
        for (int m = 0; m < 16; ++m) { Tr[c][m] = 0.0f; Ti[c][m] = 0.0f; }

    float Wr[16], Wi[16], Sr[16], Si[16];
#pragma unroll
    for (int m = 0; m < 16; ++m) {
        float2 i0 = tw[(m * h0) & 255];
        Wr[m] = i0.x; Wi[m] = -i0.y;
        float2 st = tw[m];
        Sr[m] = st.x; Si[m] = -st.y;
    }

    // radix-4 over h: rows h, h+64, h+128, h+192; i^m -> class tricks
    for (int j = 0; j < 16; ++j) {
        const int h = h0 + j;
        const float4 v0 = xq[h * 64 + l];
        const float4 v1 = xq[(h + 64) * 64 + l];
        const float4 v2 = xq[(h + 128) * 64 + l];
        const float4 v3 = xq[(h + 192) * 64 + l];
        const float a[4]  = {v0.x + v2.x, v0.y + v2.y, v0.z + v2.z, v0.w + v2.w};
        const float bb[4] = {v0.x - v2.x, v0.y - v2.y, v0.z - v2.z, v0.w - v2.w};
        const float cc[4] = {v1.x + v3.x, v1.y + v3.y, v1.z + v3.z, v1.w + v3.w};
        const float d[4]  = {v1.x - v3.x, v1.y - v3.y, v1.z - v3.z, v1.w - v3.w};
        float se0[4], se2[4];
#pragma unroll
        for (int c = 0; c < 4; ++c) { se0[c] = a[c] + cc[c]; se2[c] = a[c] - cc[c]; }

#pragma unroll
        for (int m = 0; m < 16; ++m) {
            const float wr = Wr[m], wi2 = Wi[m];
            if ((m & 3) == 0) {
#pragma unroll
                for (int c = 0; c < 4; ++c) {
                    Tr[c][m] = fmaf(se0[c], wr,  Tr[c][m]);
                    Ti[c][m] = fmaf(se0[c], wi2, Ti[c][m]);
                }
            } else if ((m & 3) == 2) {
#pragma unroll
                for (int c = 0; c < 4; ++c) {
                    Tr[c][m] = fmaf(se2[c], wr,  Tr[c][m]);
                    Ti[c][m] = fmaf(se2[c], wi2, Ti[c][m]);
                }
            } else if ((m & 3) == 1) {   // s = b - i d
#pragma unroll
                for (int c = 0; c < 4; ++c) {
                    Tr[c][m] = fmaf(bb[c], wr,  Tr[c][m]);
                    Tr[c][m] = fmaf(d[c],  wi2, Tr[c][m]);
                    Ti[c][m] = fmaf(bb[c], wi2, Ti[c][m]);
                    Ti[c][m] = fmaf(-d[c], wr,  Ti[c][m]);
                }
            } else {                     // s = b + i d
#pragma unroll
                for (int c = 0; c < 4; ++c) {
                    Tr[c][m] = fmaf(bb[c], wr,  Tr[c][m]);
                    Tr[c][m] = fmaf(-d[c], wi2, Tr[c][m]);
                    Ti[c][m] = fmaf(bb[c], wi2, Ti[c][m]);
                    Ti[c][m] = fmaf(d[c],  wr,  Ti[c][m]);
                }
            }
            const float nr = fmaf(wr, Sr[m], -wi2 * Si[m]);  // W *= S
            Wi[m] = fmaf(wr, Si[m], wi2 * Sr[m]);
            Wr[m] = nr;
        }
    }

    // cross-wave reduce into Ts, 4 m-groups of 4
#pragma unroll
    for (int mg = 0; mg < 4; ++mg) {
        if (mg) __syncthreads();
#pragma unroll
        for (int mm = 0; mm < 4; ++mm)
#pragma unroll
            for (int c = 0; c < 4; ++c)
                red[wv][mm][c][l] = make_float2(Tr[c][mg * 4 + mm], Ti[c][mg * 4 + mm]);
        __syncthreads();
        const int mq = t >> 6, idx = t & 63;
#pragma unroll
        for (int c = 0; c < 4; ++c) {
            float2 a0 = red[0][mq][c][idx], a1 = red[1][mq][c][idx];
            float2 a2 = red[2][mq][c][idx], a3 = red[3][mq][c][idx];
            Ts[mg * 4 + mq][c][idx] =
                make_float2(a0.x + a1.x + a2.x + a3.x, a0.y + a1.y + a2.y + a3.y);
        }
    }
    __syncthreads();                      // red dead; P may overwrite

    // parity precombine: P[m][p][w] = T[m][w] + (-1)^p T[m][w+128], w<128
#pragma unroll
    for (int k = 0; k < 8; ++k) {
        const int s = k * 256 + t;        // 16m x 128w slots
        const int m = s >> 7, w = s & 127;
        const int c = w & 3, li = w >> 2;
        float2 A = Ts[m][c][li], Bv = Ts[m][c][li + 32];
        P[m][0][w] = make_float2(A.x + Bv.x, A.y + Bv.y);
        P[m][1][w] = make_float2(A.x - Bv.x, A.y - Bv.y);
    }
    __syncthreads();                      // Ts dead; Q may overwrite

    // quarter planes: Q[m][n&3][w<64] = P[m][n&1][w] + (-i)^n P[m][n&1][w+64]
#pragma unroll
    for (int k = 0; k < 4; ++k) {
        const int s = k * 256 + t;        // 16m x 64w tasks
        const int m = s >> 6, w = s & 63;
        float2 a0 = P[m][0][w], b0 = P[m][0][w + 64];
        float2 a1 = P[m][1][w], b1 = P[m][1][w + 64];
        Q[m][0][w] = make_float2(a0.x + b0.x, a0.y + b0.y);
        Q[m][2][w] = make_float2(a0.x - b0.x, a0.y - b0.y);
        Q[m][1][w] = make_float2(a1.x + b1.y, a1.y - b1.x);   // + (-i)*b1
        Q[m][3][w] = make_float2(a1.x - b1.y, a1.y + b1.x);   // + (+i)*b1
    }
    __syncthreads();

    // w-DFT tail: thread (m = t>>4, n = t&15), 64 iters on quarter plane
    const int m = t >> 4, n = t & 15;
    const float2* Qp = &Q[m][n & 3][0];
    float ang = (2.0f * PI_F / 256.0f) * (float)n;
    float c1 = __cosf(ang), s1 = __sinf(ang);
    float cr = 1.0f, ci = 0.0f;
    float ar = 0.0f, ai = 0.0f;
    for (int w = 0; w < 64; ++w) {
        float2 Tv = Qp[w];
        ar += Tv.x * cr + Tv.y * ci;     // * e^{-i n w}
        ai += Tv.y * cr - Tv.x * ci;
        float nr = fmaf(cr, c1, -ci * s1);
        float nc = fmaf(cr, s1, ci * c1);
        cr = nr; ci = nc;
    }
    xsub[(size_t)bi * 256 + t] = make_float2(ar, ai);
}

__global__ __launch_bounds__(256, 4) void kI(const float2* __restrict__ xsub,
                                             const float* __restrict__ wr,
                                             const float* __restrict__ wi,
                                             float* __restrict__ y) {
    __shared__ float2 tw[256];           // 2 KB
    __shared__ float2 os[256];           // 2 KB
    __shared__ float2 U[16][256];        // 32 KB  -> 36 KB total, 4 blocks/CU
    const int t = threadIdx.x;
    { float ang = (2.0f * PI_F / 256.0f) * (float)t;
      tw[t] = make_float2(__cosf(ang), __sinf(ang)); }

    const int idx = blockIdx.x, bo = idx >> 1, hq = idx & 1;
    const int b = bo >> 5, o = bo & 31;

    // stage 1: channel mix over Cin (duplicated per hq; L2/L3-served re-reads)
    {
        float ar = 0.0f, ai = 0.0f;
#pragma unroll 8
        for (int i = 0; i < 32; ++i) {
            float2 xv = xsub[(size_t)(b * 32 + i) * 256 + t];
            float wre = wr[(size_t)(i * 32 + o) * 256 + t];
            float wim = wi[(size_t)(i * 32 + o) * 256 + t];
            ar += xv.x * wre - xv.y * wim;
            ai += xv.x * wim + xv.y * wre;
        }
        os[t] = make_float2(ar, ai);
    }
    __syncthreads();

    // stage 2: radix-2 over w fills U[m][w0], U[m][w0+128] (duplicated)
    {
        const int w0 = t & 127, mh = t >> 7;
        float twr[16], twi[16];
#pragma unroll
        for (int n = 0; n < 16; ++n) {
            float2 cs = tw[(n * w0) & 255];
            twr[n] = cs.x; twi[n] = cs.y;
        }
#pragma unroll
        for (int mm = 0; mm < 8; ++mm) {
            const int m = mh * 8 + mm;
            float u0r = 0.f, u0i = 0.f, u1r = 0.f, u1i = 0.f;
#pragma unroll
            for (int n = 0; n < 16; ++n) {
                float2 ov = os[m * 16 + n];          // uniform -> broadcast
                float tr = ov.x * twr[n] - ov.y * twi[n];   // * e^{+i n w0}
                float ti2 = ov.x * twi[n] + ov.y * twr[n];
                u0r += tr; u0i += ti2;
                if (n & 1) { u1r -= tr; u1i -= ti2; }
                else       { u1r += tr; u1i += ti2; }
            }
            U[m][w0]       = make_float2(u0r, u0i);
            U[m][w0 + 128] = make_float2(u1r, u1i);
        }
    }
    __syncthreads();

    // stage 3: radix-4 inverse h-DFT, h-split: this block covers base rows
    // h in [hq*32, hq*32+32). Lane owns ONE column w = wv*64 + l
    // (U preload = 32 VGPR), stores 256B contiguous per wave-row.
    const int l = t & 63, wv = t >> 6;
    const int w = wv * 64 + l;
    float Ur[16], Ui[16];
#pragma unroll
    for (int m = 0; m < 16; ++m) { float2 u = U[m][w]; Ur[m] = u.x; Ui[m] = u.y; }

    const int h0 = hq * 32;
    float Rr[16], Ri[16], Sr[16], Si[16];
#pragma unroll
    for (int m = 0; m < 16; ++m) {
        float2 i0 = tw[(m * h0) & 255];
        Rr[m] = i0.x; Ri[m] = i0.y;      // e^{+i m h0}
        float2 st = tw[m];
        Sr[m] = st.x; Si[m] = st.y;      // e^{+i m}
    }

    float* yp = y + (size_t)bo * 65536 + w;
    const float inv = 1.0f / 65536.0f;
    for (int j = 0; j < 32; ++j) {
        const int h = h0 + j;
        float A0 = 0.f, A1 = 0.f, A2 = 0.f, A3 = 0.f, B1 = 0.f, B3 = 0.f;
#pragma unroll
        for (int m = 0; m < 16; ++m) {
            const float cr = Rr[m], ci = Ri[m];
            if ((m & 3) == 0) {
                A0 = fmaf(Ur[m], cr, A0); A0 = fmaf(-Ui[m], ci, A0);
            } else if ((m & 3) == 2) {
                A2 = fmaf(Ur[m], cr, A2); A2 = fmaf(-Ui[m], ci, A2);
            } else if ((m & 3) == 1) {
                A1 = fmaf(Ur[m], cr, A1); A1 = fmaf(-Ui[m], ci, A1);
                B1 = fmaf(Ur[m], ci, B1); B1 = fmaf(Ui[m], cr, B1);
            } else {
                A3 = fmaf(Ur[m], cr, A3); A3 = fmaf(-Ui[m], ci, A3);
                B3 = fmaf(Ur[m], ci, B3); B3 = fmaf(Ui[m], cr, B3);
            }
            Rr[m] = fmaf(cr, Sr[m], -ci * Si[m]);     // R *= S
            Ri[m] = fmaf(cr, Si[m],  ci * Sr[m]);
        }
        // y(h)=A0+A1+A2+A3; y(h+64)=A0-B1-A2+B3; y(h+128)=A0-A1+A2-A3; y(h+192)=A0+B1-A2-B3
        const float p = A0 + A2, q = A1 + A3;
        const float r = A0 - A2, s = B3 - B1;
        yp[h * 256]         = (p + q) * inv;
        yp[(h + 128) * 256] = (p - q) * inv;
        yp[(h + 64) * 256]  = (r + s) * inv;
        yp[(h + 192) * 256] = (r - s) * inv;
    }
}

extern "C" void kernel_launch(void* const* d_in, const int* in_sizes, int n_in,
                              void* d_out, int out_size, void* d_ws, size_t ws_size,
                              hipStream_t stream) {
    const float* x  = (const float*)d_in[0];   // [16][32][256][256]
    const float* wr = (const float*)d_in[1];   // [32][32][16][16]
    const float* wi = (const float*)d_in[2];   // [32][32][16][16]
    float* y = (float*)d_out;                  // [16][32][256][256]

    float2* xsub = (float2*)d_ws;              // 512*256*8 = 1 MB

    kF<<<512,  256, 0, stream>>>(x, xsub);
    kI<<<1024, 256, 0, stream>>>(xsub, wr, wi, y);
}

// Round 22
// 67.600 us; speedup vs baseline: 1.2306x; 1.2306x over previous
//
#include <hip/hip_runtime.h>
#include <hip/hip_bf16.h>
#include <math.h>

// SpectralConv2d (FNO): B=16, Cin=Cout=32, H=W=256, MODES=16x16.
// R20 structure (70.4us) + two more serial-phase radix cuts:
//  - kF tail radix-8: O[m][n&7][v<32] planes -> 32-iter tail
//  - kI stage-2 radix-4 over w: i^{nk} group accumulators -> half the cmuls
//  kF (b,i): T (radix-4 over h) -> P (+128 parity) -> Q (+64, (-i)^n)
//            -> O (+32, e^{-i pi n/4}) -> xsub[m][n] = 32-iter DFT on O
//  kI (b,o): os = sum_i xsub*W; U via radix-4 over w; y = radix-4 inverse h-DFT.

#define PI_F 3.14159265358979323846f

__global__ __launch_bounds__(256, 2) void kF(const float* __restrict__ x,
                                             float2* __restrict__ xsub) {
    __shared__ float2 tw[256];
    __shared__ float2 Ts[16][4][65];     // [m][c][l]; later overlaid by Q[16][4][65]
    __shared__ float2 redP[4224];        // union: red[4][4][4][64] / P[16][2][129] / O[16][8][33]
    auto red = reinterpret_cast<float2 (*)[4][4][64]>(redP);
    auto P   = reinterpret_cast<float2 (*)[2][129]>(redP);
    auto O   = reinterpret_cast<float2 (*)[8][33]>(redP);
    auto Q   = reinterpret_cast<float2 (*)[4][65]>(&Ts[0][0][0]);   // [16][4][65]

    const int t = threadIdx.x;
    { float ang = (2.0f * PI_F / 256.0f) * (float)t;
      tw[t] = make_float2(__cosf(ang), __sinf(ang)); }
    __syncthreads();

    const int bi = blockIdx.x;
    const float4* xq = (const float4*)(x + (size_t)bi * 65536);  // row r -> xq[r*64+l]
    const int l = t & 63, wv = t >> 6;
    const int h0 = wv * 16;              // wave covers h0..h0+15 (x4 rows each)

    float Tr[4][16], Ti[4][16];          // [c][m]
#pragma unroll
    for (int c = 0; c < 4; ++c)
#pragma unroll
        for (int m = 0; m < 16; ++m) { Tr[c][m] = 0.0f; Ti[c][m] = 0.0f; }

    float Wr[16], Wi[16], Sr[16], Si[16];
#pragma unroll
    for (int m = 0; m < 16; ++m) {
        float2 i0 = tw[(m * h0) & 255];
        Wr[m] = i0.x; Wi[m] = -i0.y;
        float2 st = tw[m];
        Sr[m] = st.x; Si[m] = -st.y;
    }

    // radix-4 over h: rows h, h+64, h+128, h+192; i^m -> class tricks
    for (int j = 0; j < 16; ++j) {
        const int h = h0 + j;
        const float4 v0 = xq[h * 64 + l];
        const float4 v1 = xq[(h + 64) * 64 + l];
        const float4 v2 = xq[(h + 128) * 64 + l];
        const float4 v3 = xq[(h + 192) * 64 + l];
        const float a[4]  = {v0.x + v2.x, v0.y + v2.y, v0.z + v2.z, v0.w + v2.w};
        const float bb[4] = {v0.x - v2.x, v0.y - v2.y, v0.z - v2.z, v0.w - v2.w};
        const float cc[4] = {v1.x + v3.x, v1.y + v3.y, v1.z + v3.z, v1.w + v3.w};
        const float d[4]  = {v1.x - v3.x, v1.y - v3.y, v1.z - v3.z, v1.w - v3.w};
        float se0[4], se2[4];
#pragma unroll
        for (int c = 0; c < 4; ++c) { se0[c] = a[c] + cc[c]; se2[c] = a[c] - cc[c]; }

#pragma unroll
        for (int m = 0; m < 16; ++m) {
            const float wr = Wr[m], wi2 = Wi[m];
            if ((m & 3) == 0) {
#pragma unroll
                for (int c = 0; c < 4; ++c) {
                    Tr[c][m] = fmaf(se0[c], wr,  Tr[c][m]);
                    Ti[c][m] = fmaf(se0[c], wi2, Ti[c][m]);
                }
            } else if ((m & 3) == 2) {
#pragma unroll
                for (int c = 0; c < 4; ++c) {
                    Tr[c][m] = fmaf(se2[c], wr,  Tr[c][m]);
                    Ti[c][m] = fmaf(se2[c], wi2, Ti[c][m]);
                }
            } else if ((m & 3) == 1) {   // s = b - i d
#pragma unroll
                for (int c = 0; c < 4; ++c) {
                    Tr[c][m] = fmaf(bb[c], wr,  Tr[c][m]);
                    Tr[c][m] = fmaf(d[c],  wi2, Tr[c][m]);
                    Ti[c][m] = fmaf(bb[c], wi2, Ti[c][m]);
                    Ti[c][m] = fmaf(-d[c], wr,  Ti[c][m]);
                }
            } else {                     // s = b + i d
#pragma unroll
                for (int c = 0; c < 4; ++c) {
                    Tr[c][m] = fmaf(bb[c], wr,  Tr[c][m]);
                    Tr[c][m] = fmaf(-d[c], wi2, Tr[c][m]);
                    Ti[c][m] = fmaf(bb[c], wi2, Ti[c][m]);
                    Ti[c][m] = fmaf(d[c],  wr,  Ti[c][m]);
                }
            }
            const float nr = fmaf(wr, Sr[m], -wi2 * Si[m]);  // W *= S
            Wi[m] = fmaf(wr, Si[m], wi2 * Sr[m]);
            Wr[m] = nr;
        }
    }

    // cross-wave reduce into Ts, 4 m-groups of 4
#pragma unroll
    for (int mg = 0; mg < 4; ++mg) {
        if (mg) __syncthreads();
#pragma unroll
        for (int mm = 0; mm < 4; ++mm)
#pragma unroll
            for (int c = 0; c < 4; ++c)
                red[wv][mm][c][l] = make_float2(Tr[c][mg * 4 + mm], Ti[c][mg * 4 + mm]);
        __syncthreads();
        const int mq = t >> 6, idx = t & 63;
#pragma unroll
        for (int c = 0; c < 4; ++c) {
            float2 a0 = red[0][mq][c][idx], a1 = red[1][mq][c][idx];
            float2 a2 = red[2][mq][c][idx], a3 = red[3][mq][c][idx];
            Ts[mg * 4 + mq][c][idx] =
                make_float2(a0.x + a1.x + a2.x + a3.x, a0.y + a1.y + a2.y + a3.y);
        }
    }
    __syncthreads();                      // red dead; P may overwrite

    // parity precombine: P[m][p][w] = T[m][w] + (-1)^p T[m][w+128], w<128
#pragma unroll
    for (int k = 0; k < 8; ++k) {
        const int s = k * 256 + t;        // 16m x 128w slots
        const int m = s >> 7, w = s & 127;
        const int c = w & 3, li = w >> 2;
        float2 A = Ts[m][c][li], Bv = Ts[m][c][li + 32];
        P[m][0][w] = make_float2(A.x + Bv.x, A.y + Bv.y);
        P[m][1][w] = make_float2(A.x - Bv.x, A.y - Bv.y);
    }
    __syncthreads();                      // Ts dead; Q may overwrite

    // quarter planes: Q[m][n&3][w<64] = P[m][n&1][w] + (-i)^n P[m][n&1][w+64]
#pragma unroll
    for (int k = 0; k < 4; ++k) {
        const int s = k * 256 + t;        // 16m x 64w tasks
        const int m = s >> 6, w = s & 63;
        float2 a0 = P[m][0][w], b0 = P[m][0][w + 64];
        float2 a1 = P[m][1][w], b1 = P[m][1][w + 64];
        Q[m][0][w] = make_float2(a0.x + b0.x, a0.y + b0.y);
        Q[m][2][w] = make_float2(a0.x - b0.x, a0.y - b0.y);
        Q[m][1][w] = make_float2(a1.x + b1.y, a1.y - b1.x);   // + (-i)*b1
        Q[m][3][w] = make_float2(a1.x - b1.y, a1.y + b1.x);   // + (+i)*b1
    }
    __syncthreads();                      // P dead; O may overwrite

    // eighth planes: O[m][n&7][v<32] = Q[m][n&3][v] + e^{-i pi n/4} Q[m][n&3][v+32]
    {
        const float SQ = 0.70710678118654752f;
#pragma unroll
        for (int k = 0; k < 2; ++k) {
            const int s = k * 256 + t;    // 16m x 32v tasks
            const int m = s >> 5, v = s & 31;
            float2 q0a = Q[m][0][v], q0b = Q[m][0][v + 32];
            float2 q1a = Q[m][1][v], q1b = Q[m][1][v + 32];
            float2 q2a = Q[m][2][v], q2b = Q[m][2][v + 32];
            float2 q3a = Q[m][3][v], q3b = Q[m][3][v + 32];
            O[m][0][v] = make_float2(q0a.x + q0b.x, q0a.y + q0b.y);
            O[m][4][v] = make_float2(q0a.x - q0b.x, q0a.y - q0b.y);
            O[m][2][v] = make_float2(q2a.x + q2b.y, q2a.y - q2b.x);   // + (-i) q2b
            O[m][6][v] = make_float2(q2a.x - q2b.y, q2a.y + q2b.x);   // + (+i) q2b
            const float u1 = SQ * (q1b.x + q1b.y), w1 = SQ * (q1b.y - q1b.x);
            O[m][1][v] = make_float2(q1a.x + u1, q1a.y + w1);         // * (1-i)/sqrt2
            O[m][5][v] = make_float2(q1a.x - u1, q1a.y - w1);
            const float u3 = SQ * (q3b.x + q3b.y), w3 = SQ * (q3b.y - q3b.x);
            O[m][3][v] = make_float2(q3a.x + w3, q3a.y - u3);         // * (-1-i)/sqrt2
            O[m][7][v] = make_float2(q3a.x - w3, q3a.y + u3);
        }
    }
    __syncthreads();

    // w-DFT tail: thread (m = t>>4, n = t&15), 32 iters on eighth plane
    const int m = t >> 4, n = t & 15;
    const float2* Op = &O[m][n & 7][0];
    float ang = (2.0f * PI_F / 256.0f) * (float)n;
    float c1 = __cosf(ang), s1 = __sinf(ang);
    float cr = 1.0f, ci = 0.0f;
    float ar = 0.0f, ai = 0.0f;
    for (int v = 0; v < 32; ++v) {
        float2 Tv = Op[v];
        ar += Tv.x * cr + Tv.y * ci;     // * e^{-i n v}
        ai += Tv.y * cr - Tv.x * ci;
        float nr = fmaf(cr, c1, -ci * s1);
        float nc = fmaf(cr, s1, ci * c1);
        cr = nr; ci = nc;
    }
    xsub[(size_t)bi * 256 + t] = make_float2(ar, ai);
}

__global__ __launch_bounds__(256, 2) void kI(const float2* __restrict__ xsub,
                                             const float* __restrict__ wr,
                                             const float* __restrict__ wi,
                                             float* __restrict__ y) {
    __shared__ float2 tw[256];
    __shared__ float2 os[256];
    __shared__ float2 U[16][256];        // 32 KB
    const int t = threadIdx.x;
    { float ang = (2.0f * PI_F / 256.0f) * (float)t;
      tw[t] = make_float2(__cosf(ang), __sinf(ang)); }

    const int bo = blockIdx.x, b = bo >> 5, o = bo & 31;

    // stage 1: channel mix over Cin
    {
        float ar = 0.0f, ai = 0.0f;
#pragma unroll 8
        for (int i = 0; i < 32; ++i) {
            float2 xv = xsub[(size_t)(b * 32 + i) * 256 + t];
            float wre = wr[(size_t)(i * 32 + o) * 256 + t];
            float wim = wi[(size_t)(i * 32 + o) * 256 + t];
            ar += xv.x * wre - xv.y * wim;
            ai += xv.x * wim + xv.y * wre;
        }
        os[t] = make_float2(ar, ai);
    }
    __syncthreads();

    // stage 2: radix-4 over w: thread (mh = t>>6, w0 = t&63) fills
    // U[m][w0+64k], k=0..3 via i^{nk} group accumulators
    {
        const int w0 = t & 63, mh = t >> 6;
        float twr[16], twi[16];
#pragma unroll
        for (int n = 0; n < 16; ++n) {
            float2 cs = tw[(n * w0) & 255];
            twr[n] = cs.x; twi[n] = cs.y;
        }
#pragma unroll
        for (int mm = 0; mm < 4; ++mm) {
            const int m = mh * 4 + mm;
            float G0r = 0.f, G0i = 0.f, G1r = 0.f, G1i = 0.f;
            float G2r = 0.f, G2i = 0.f, G3r = 0.f, G3i = 0.f;
#pragma unroll
            for (int n = 0; n < 16; ++n) {
                float2 ov = os[m * 16 + n];          // uniform -> broadcast
                if ((n & 3) == 0) {
                    G0r = fmaf(ov.x, twr[n], G0r); G0r = fmaf(-ov.y, twi[n], G0r);
                    G0i = fmaf(ov.x, twi[n], G0i); G0i = fmaf(ov.y, twr[n], G0i);
                } else if ((n & 3) == 1) {
                    G1r = fmaf(ov.x, twr[n], G1r); G1r = fmaf(-ov.y, twi[n], G1r);
                    G1i = fmaf(ov.x, twi[n], G1i); G1i = fmaf(ov.y, twr[n], G1i);
                } else if ((n & 3) == 2) {
                    G2r = fmaf(ov.x, twr[n], G2r); G2r = fmaf(-ov.y, twi[n], G2r);
                    G2i = fmaf(ov.x, twi[n], G2i); G2i = fmaf(ov.y, twr[n], G2i);
                } else {
                    G3r = fmaf(ov.x, twr[n], G3r); G3r = fmaf(-ov.y, twi[n], G3r);
                    G3i = fmaf(ov.x, twi[n], G3i); G3i = fmaf(ov.y, twr[n], G3i);
                }
            }
            // U[w0+64k] = G0 + i^k G1 + (-1)^k G2 + (-i)^k G3
            U[m][w0]       = make_float2(G0r + G1r + G2r + G3r, G0i + G1i + G2i + G3i);
            U[m][w0 + 64]  = make_float2(G0r - G1i - G2r + G3i, G0i + G1r - G2i - G3r);
            U[m][w0 + 128] = make_float2(G0r - G1r + G2r - G3r, G0i - G1i + G2i - G3i);
            U[m][w0 + 192] = make_float2(G0r + G1i - G2r - G3i, G0i - G1r - G2i + G3r);
        }
    }
    __syncthreads();

    // stage 3: radix-4 inverse h-DFT (R20-verbatim). Lane owns w = 4l..4l+3.
    const int l = t & 63, wv = t >> 6;
    const int h0 = wv * 16;
    float Ur[4][16], Ui[4][16];
#pragma unroll
    for (int m = 0; m < 16; ++m) {
        const float4* Um = (const float4*)&U[m][0];
        float4 p0 = Um[2 * l], p1 = Um[2 * l + 1];
        Ur[0][m] = p0.x; Ui[0][m] = p0.y; Ur[1][m] = p0.z; Ui[1][m] = p0.w;
        Ur[2][m] = p1.x; Ui[2][m] = p1.y; Ur[3][m] = p1.z; Ui[3][m] = p1.w;
    }
    float Rr[16], Ri[16], Sr[16], Si[16];
#pragma unroll
    for (int m = 0; m < 16; ++m) {
        float2 i0 = tw[(m * h0) & 255];
        Rr[m] = i0.x; Ri[m] = i0.y;      // e^{+i m h0}
        float2 st = tw[m];
        Sr[m] = st.x; Si[m] = st.y;      // e^{+i m}
    }

    float* yp = y + (size_t)bo * 65536;
    const float inv = 1.0f / 65536.0f;
    for (int j = 0; j < 16; ++j) {
        const int h = h0 + j;
        float A0[4] = {0,0,0,0}, A1[4] = {0,0,0,0}, A2[4] = {0,0,0,0};
        float A3[4] = {0,0,0,0}, B1[4] = {0,0,0,0}, B3[4] = {0,0,0,0};
#pragma unroll
        for (int m = 0; m < 16; ++m) {
            const float cr = Rr[m], ci = Ri[m];
            if ((m & 3) == 0) {
#pragma unroll
                for (int c = 0; c < 4; ++c) {
                    A0[c] = fmaf(Ur[c][m], cr, A0[c]);
                    A0[c] = fmaf(-Ui[c][m], ci, A0[c]);
                }
            } else if ((m & 3) == 2) {
#pragma unroll
                for (int c = 0; c < 4; ++c) {
                    A2[c] = fmaf(Ur[c][m], cr, A2[c]);
                    A2[c] = fmaf(-Ui[c][m], ci, A2[c]);
                }
            } else if ((m & 3) == 1) {
#pragma unroll
                for (int c = 0; c < 4; ++c) {
                    A1[c] = fmaf(Ur[c][m], cr, A1[c]);
                    A1[c] = fmaf(-Ui[c][m], ci, A1[c]);
                    B1[c] = fmaf(Ur[c][m], ci, B1[c]);
                    B1[c] = fmaf(Ui[c][m], cr, B1[c]);
                }
            } else {
#pragma unroll
                for (int c = 0; c < 4; ++c) {
                    A3[c] = fmaf(Ur[c][m], cr, A3[c]);
                    A3[c] = fmaf(-Ui[c][m], ci, A3[c]);
                    B3[c] = fmaf(Ur[c][m], ci, B3[c]);
                    B3[c] = fmaf(Ui[c][m], cr, B3[c]);
                }
            }
            Rr[m] = fmaf(cr, Sr[m], -ci * Si[m]);        // R *= S
            Ri[m] = fmaf(cr, Si[m],  ci * Sr[m]);
        }
        float4 y0, y1, y2, y3;
        float* o0 = &y0.x; float* o1 = &y1.x; float* o2 = &y2.x; float* o3 = &y3.x;
#pragma unroll
        for (int c = 0; c < 4; ++c) {
            const float p = A0[c] + A2[c], q = A1[c] + A3[c];
            const float r = A0[c] - A2[c], s = B3[c] - B1[c];
            o0[c] = (p + q) * inv;
            o2[c] = (p - q) * inv;
            o1[c] = (r + s) * inv;
            o3[c] = (r - s) * inv;
        }
        ((float4*)(yp + h * 256))[l]         = y0;
        ((float4*)(yp + (h + 64) * 256))[l]  = y1;
        ((float4*)(yp + (h + 128) * 256))[l] = y2;
        ((float4*)(yp + (h + 192) * 256))[l] = y3;
    }
}

extern "C" void kernel_launch(void* const* d_in, const int* in_sizes, int n_in,
                              void* d_out, int out_size, void* d_ws, size_t ws_size,
                              hipStream_t stream) {
    const float* x  = (const float*)d_in[0];   // [16][32][256][256]
    const float* wr = (const float*)d_in[1];   // [32][32][16][16]
    const float* wi = (const float*)d_in[2];   // [32][32][16][16]
    float* y = (float*)d_out;                  // [16][32][256][256]

    float2* xsub = (float2*)d_ws;              // 512*256*8 = 1 MB

    kF<<<512, 256, 0, stream>>>(x, xsub);
    kI<<<512, 256, 0, stream>>>(xsub, wr, wi, y);
}